// Round 6
// baseline (1570.251 us; speedup 1.0000x reference)
//
#include <hip/hip_runtime.h>

// CounterFlowNetwork fused kernel for MI355X (gfx950), round 6.
// R5 post-mortem: latency-bound — occupancy 12% (1 wave/SIMD), MfmaUtil 10%,
// VALU 23%, HBM 4.5%. ~82 barrier phases/block, 4 sequential grid rounds,
// nothing overlaps the dependent chain. R6:
//  - Gas state in registers (f16x2, 64 VGPR), no weight reg caches -> ~160
//    VGPRs, LDS cut to 80 KB -> 2 blocks/CU (2 waves/SIMD, 2 grid rounds).
//  - Plate fusion: Wtab = alpha*Wtr@Wab, btab = alpha*btr@Wab + bab
//    (device prep) -> descending plate = 2 GEMMs/2 barriers (was 3/3).
//  - Phases ~82 -> ~66, each shorter (gas reg-read replaces 16 scalar LDS).

typedef _Float16 f16;
typedef _Float16 f16x2 __attribute__((ext_vector_type(2)));
typedef _Float16 f16x8 __attribute__((ext_vector_type(8)));
typedef float f32x4 __attribute__((ext_vector_type(4)));

#define NT 256
#define TILE_B 16
#define SLOT 8192              // one [16][256] f16 slot
#define TMPA_OFF 65536         // slot 8: DF / g8 tile
#define TMPH_OFF 73728         // slot 9: h tile
#define LDS_BYTES 81920        // 10 slots = 80 KiB -> 2 blocks/CU
#define LIQP(m) (smem + ((m) - 1) * SLOT)   // l[1..8]: slots 0..7

__device__ __forceinline__ f32x4 mfma16(f16x8 a, f16x8 b, f32x4 c) {
  return __builtin_amdgcn_mfma_f32_16x16x32_f16(a, b, c, 0, 0, 0);
}
__device__ __forceinline__ f32x4 zero4() {
  f32x4 z; z[0] = 0.f; z[1] = 0.f; z[2] = 0.f; z[3] = 0.f; return z;
}
__device__ __forceinline__ float sigm(float s) { return 1.f / (1.f + __expf(-s)); }

// A [16 x K] f16 in LDS (stride AS, XOR-swizzled); B streamed from global,
// 4 frag pointers (pre-offset by +kg*8).
template <int K, int AS>
__device__ __forceinline__ void gemm_gB(const char* aB,
                                        const f16* __restrict__ p0,
                                        const f16* __restrict__ p1,
                                        const f16* __restrict__ p2,
                                        const f16* __restrict__ p3,
                                        int l15, int kg, f32x4 (&acc)[4]) {
  const int sw = (l15 & 7) << 4;
  #pragma unroll
  for (int ks = 0; ks < (K >> 5); ++ks) {
    const int kk = (ks << 5) + (kg << 3);
    f16x8 a = *(const f16x8*)(aB + l15 * AS + ((kk * 2) ^ sw));
    acc[0] = mfma16(a, *(const f16x8*)(p0 + (ks << 5)), acc[0]);
    acc[1] = mfma16(a, *(const f16x8*)(p1 + (ks << 5)), acc[1]);
    acc[2] = mfma16(a, *(const f16x8*)(p2 + (ks << 5)), acc[2]);
    acc[3] = mfma16(a, *(const f16x8*)(p3 + (ks << 5)), acc[3]);
  }
}

// write 16 C-frag values as f16 into swizzled [16][256] LDS tile
__device__ __forceinline__ void store16(char* buf, int w, int l15, int kg,
                                        const float* v) {
  #pragma unroll
  for (int q = 0; q < 16; ++q) {
    const int r = kg * 4 + (q & 3);
    const int c = w * 64 + ((q >> 2) << 4) + l15;
    *(f16*)(buf + r * 512 + ((c * 2) ^ ((r & 7) << 4))) = (f16)v[q];
  }
}

// packed gas accessors — switch keeps indices static (rule: runtime-indexed
// ext_vector arrays go to scratch)
#define GH_RD(S) { _Pragma("unroll") for (int q = 0; q < 16; ++q) v[q] = (float)gh[S][q >> 1][q & 1]; }
__device__ __forceinline__ void gh_read(const f16x2 (&gh)[8][8], int s, float* v) {
  switch (s) {
    case 0: GH_RD(0) break; case 1: GH_RD(1) break; case 2: GH_RD(2) break;
    case 3: GH_RD(3) break; case 4: GH_RD(4) break; case 5: GH_RD(5) break;
    case 6: GH_RD(6) break; default: GH_RD(7) break;
  }
}
#define GH_WR(S) { _Pragma("unroll") for (int q = 0; q < 16; ++q) gh[S][q >> 1][q & 1] = (f16)v[q]; }
__device__ __forceinline__ void gh_write(f16x2 (&gh)[8][8], int s, const float* v) {
  switch (s) {
    case 1: GH_WR(1) break; case 2: GH_WR(2) break; case 3: GH_WR(3) break;
    case 4: GH_WR(4) break; case 5: GH_WR(5) break; case 6: GH_WR(6) break;
    default: GH_WR(7) break;
  }
}

// Fused prep: five [K][N] f32 -> [Npad][K] f16 transposes (Wab dropped —
// only used via Wtab now). Npad MUST be a multiple of 32 (R4 bug).
__global__ void prep_all(const float* __restrict__ Wge, const float* __restrict__ Weq,
                         const float* __restrict__ Wtr, const float* __restrict__ W1,
                         const float* __restrict__ W2,
                         f16* __restrict__ WgeT, f16* __restrict__ WeqT,
                         f16* __restrict__ WtrT, f16* __restrict__ W1T,
                         f16* __restrict__ W2T) {
  __shared__ float ts[32][33];
  const int b = blockIdx.x;
  const float* src; f16* dst; int K, N, Npad, ti;
  if (b < 128)      { src = Wge; dst = WgeT; K = 512; N = 256;  Npad = 256;  ti = b; }
  else if (b < 192) { src = Weq; dst = WeqT; K = 256; N = 256;  Npad = 256;  ti = b - 128; }
  else if (b < 256) { src = Wtr; dst = WtrT; K = 256; N = 256;  Npad = 256;  ti = b - 192; }
  else if (b < 384) { src = W1;  dst = W1T;  K = 512; N = 256;  Npad = 256;  ti = b - 256; }
  else              { src = W2;  dst = W2T;  K = 256; N = 1000; Npad = 1024; ti = b - 384; }
  const int bnT = Npad >> 5;
  const int bk = (ti / bnT) << 5, bn = (ti % bnT) << 5;
  const int tx = threadIdx.x & 31, ty = threadIdx.x >> 5;  // 32 x 8
  #pragma unroll
  for (int i = 0; i < 32; i += 8) {
    const int k = bk + ty + i, n = bn + tx;
    ts[ty + i][tx] = (k < K && n < N) ? src[(size_t)k * N + n] : 0.f;
  }
  __syncthreads();
  #pragma unroll
  for (int i = 0; i < 32; i += 8) {
    const int n = bn + ty + i, k = bk + tx;
    if (n < Npad) dst[(size_t)n * K + k] = (f16)ts[tx][ty + i];
  }
}

// WtabT[out][k] = alpha * sum_m Wtr[k][m] * Wab[m][out]  (f16, transposed)
// btab[out]    = alpha * sum_m btr[m] * Wab[m][out] + bab[out]
__global__ void prep_wtab(const float* __restrict__ Wtr, const float* __restrict__ Wab,
                          const float* __restrict__ btr, const float* __restrict__ bab,
                          const float* __restrict__ alphap,
                          f16* __restrict__ WtabT, float* __restrict__ btab) {
  __shared__ float wcol[256];
  __shared__ float pr[256];
  const int out = blockIdx.x;          // 0..255
  const int k = threadIdx.x;           // 0..255
  wcol[k] = Wab[(size_t)k * 256 + out];
  pr[k] = btr[k] * Wab[(size_t)k * 256 + out];
  __syncthreads();
  float acc = 0.f;
  const float* wr = Wtr + (size_t)k * 256;
  #pragma unroll 4
  for (int m = 0; m < 256; ++m) acc += wr[m] * wcol[m];
  const float alpha = alphap[0];
  WtabT[(size_t)out * 256 + k] = (f16)(alpha * acc);
  if (k == 0) {
    float s = 0.f;
    for (int m = 0; m < 256; ++m) s += pr[m];
    btab[out] = alpha * s + bab[out];
  }
}

__global__ __launch_bounds__(NT, 2)
void cfn_main(const float* __restrict__ x,
              const float* __restrict__ bge, const float* __restrict__ beq,
              const float* __restrict__ btr,
              const float* __restrict__ alphap,
              const float* __restrict__ b1p, const float* __restrict__ b2p,
              const f16* __restrict__ WgeT, const f16* __restrict__ WeqT,
              const f16* __restrict__ WtrT, const f16* __restrict__ WtabT,
              const float* __restrict__ btab,
              const f16* __restrict__ W1T, const f16* __restrict__ W2T,
              float* __restrict__ out) {
  extern __shared__ char smem[];
  const int tid = threadIdx.x;
  const int lane = tid & 63;
  const int w = tid >> 6;                    // wave owns cols w*64..w*64+63
  const int l15 = lane & 15, kg = lane >> 4;
  const int r0 = blockIdx.x * TILE_B;
  const float alpha = alphap[0];
  const int sw = (l15 & 7) << 4;

  // per-frag biases (f -> col w*64 + f*16 + l15)
  float beqv[4], btrv[4], btabv[4], se[4];
  #pragma unroll
  for (int f = 0; f < 4; ++f) {
    const int c = w * 64 + f * 16 + l15;
    beqv[f] = beq[c]; btrv[f] = btr[c]; btabv[f] = btab[c];
    se[f] = sigm(beqv[f]);                   // e when l[n+1] == 0
  }

  // streamed B frag pointers (constant-indexed only)
  const f16* weq0  = WeqT  + (size_t)(w * 64 +  0 + l15) * 256 + kg * 8;
  const f16* weq1  = WeqT  + (size_t)(w * 64 + 16 + l15) * 256 + kg * 8;
  const f16* weq2  = WeqT  + (size_t)(w * 64 + 32 + l15) * 256 + kg * 8;
  const f16* weq3  = WeqT  + (size_t)(w * 64 + 48 + l15) * 256 + kg * 8;
  const f16* wtr0  = WtrT  + (size_t)(w * 64 +  0 + l15) * 256 + kg * 8;
  const f16* wtr1  = WtrT  + (size_t)(w * 64 + 16 + l15) * 256 + kg * 8;
  const f16* wtr2  = WtrT  + (size_t)(w * 64 + 32 + l15) * 256 + kg * 8;
  const f16* wtr3  = WtrT  + (size_t)(w * 64 + 48 + l15) * 256 + kg * 8;
  const f16* wtab0 = WtabT + (size_t)(w * 64 +  0 + l15) * 256 + kg * 8;
  const f16* wtab1 = WtabT + (size_t)(w * 64 + 16 + l15) * 256 + kg * 8;
  const f16* wtab2 = WtabT + (size_t)(w * 64 + 32 + l15) * 256 + kg * 8;
  const f16* wtab3 = WtabT + (size_t)(w * 64 + 48 + l15) * 256 + kg * 8;

  // ---- stage x tile -> LDS f16 [16][512] swizzled (liquid slots 0..1 area)
  {
    const int row = tid >> 4;
    const int cb = (tid & 15) << 5;
    const int rs = (row & 7) << 4;
    const float* p = x + (size_t)(r0 + row) * 512 + cb;
    #pragma unroll
    for (int i = 0; i < 4; ++i) {
      float4 u = *(const float4*)(p + i * 8);
      float4 v = *(const float4*)(p + i * 8 + 4);
      f16x8 h;
      h[0] = (f16)u.x; h[1] = (f16)u.y; h[2] = (f16)u.z; h[3] = (f16)u.w;
      h[4] = (f16)v.x; h[5] = (f16)v.y; h[6] = (f16)v.z; h[7] = (f16)v.w;
      *(f16x8*)(smem + row * 1024 + (((cb + i * 8) * 2) ^ rs)) = h;
    }
  }
  __syncthreads();

  // ---- g0 = relu(x @ W_ge + b_ge) -> packed f16 gas regs, all 8 slots ----
  f16x2 gh[8][8];
  {
    f32x4 acc[4] = {zero4(), zero4(), zero4(), zero4()};
    const f16* g0 = WgeT + (size_t)(w * 64 +  0 + l15) * 512 + kg * 8;
    const f16* g1 = WgeT + (size_t)(w * 64 + 16 + l15) * 512 + kg * 8;
    const f16* g2 = WgeT + (size_t)(w * 64 + 32 + l15) * 512 + kg * 8;
    const f16* g3 = WgeT + (size_t)(w * 64 + 48 + l15) * 512 + kg * 8;
    gemm_gB<512, 1024>(smem, g0, g1, g2, g3, l15, kg, acc);
    #pragma unroll
    for (int q = 0; q < 16; ++q) {
      const float bv = bge[w * 64 + ((q >> 2) << 4) + l15];
      float v2 = acc[q >> 2][q & 3] + bv;
      v2 = v2 > 0.f ? v2 : 0.f;
      const f16 hv = (f16)v2;
      #pragma unroll
      for (int s = 0; s < 8; ++s) gh[s][q >> 1][q & 1] = hv;
    }
  }
  __syncthreads();                           // x reads done; slots -> liquid

  float G8[16];
  #pragma unroll
  for (int q = 0; q < 16; ++q) G8[q] = 0.f;

  #pragma unroll 1
  for (int sweep = 0; sweep < 2; ++sweep) {
    // ===== descending liquid sweep: n = 8..1 (2 phases/plate) =====
    #pragma unroll 1
    for (int n = 8; n >= 1; --n) {
      float v[16];
      gh_read(gh, n - 1, v);                 // g[n-1] from regs
      float DF[16];
      if (n == 8) {                          // l[9] == 0
        #pragma unroll
        for (int q = 0; q < 16; ++q) DF[q] = v[q] - se[q >> 2];
      } else {
        f32x4 acc[4] = {zero4(), zero4(), zero4(), zero4()};
        gemm_gB<256, 512>(LIQP(n + 1), weq0, weq1, weq2, weq3, l15, kg, acc);
        #pragma unroll
        for (int q = 0; q < 16; ++q)
          DF[q] = v[q] - sigm(acc[q >> 2][q & 3] + beqv[q >> 2]);
      }
      store16(smem + TMPA_OFF, w, l15, kg, DF);  // prev readers barrier'd
      __syncthreads();
      {                                      // l[n] = l[n+1] + DF@Wtab + btab
        f32x4 acc[4] = {zero4(), zero4(), zero4(), zero4()};
        gemm_gB<256, 512>(smem + TMPA_OFF, wtab0, wtab1, wtab2, wtab3, l15, kg, acc);
        char* dst = LIQP(n);
        const char* prv = LIQP(n + 1);       // guarded: only deref when n<8
        #pragma unroll
        for (int q = 0; q < 16; ++q) {
          const int r = kg * 4 + (q & 3);
          const int c = w * 64 + ((q >> 2) << 4) + l15;
          const int off = r * 512 + ((c * 2) ^ ((r & 7) << 4));
          float lp = 0.f;
          if (n < 8) lp = (float)*(const f16*)(prv + off);
          *(f16*)(dst + off) = (f16)(lp + acc[q >> 2][q & 3] + btabv[q >> 2]);
        }
      }
      __syncthreads();                       // l[n] visible; tmpA reusable
    }
    // ===== ascending gas sweep: n = 1..nmax (2 phases/plate) =====
    const int nmax = (sweep == 0) ? 7 : 8;   // sweep-0 g[8] dead
    #pragma unroll 1
    for (int n = 1; n <= nmax; ++n) {
      float v[16];
      gh_read(gh, n - 1, v);
      float DF[16];
      {
        f32x4 acc[4] = {zero4(), zero4(), zero4(), zero4()};
        gemm_gB<256, 512>(LIQP(n), weq0, weq1, weq2, weq3, l15, kg, acc);
        #pragma unroll
        for (int q = 0; q < 16; ++q)
          DF[q] = v[q] - sigm(acc[q >> 2][q & 3] + beqv[q >> 2]);
      }
      store16(smem + TMPA_OFF, w, l15, kg, DF);  // prev tr-readers barrier'd
      __syncthreads();
      {                                      // g[n] = g[n-1] - alpha*(DF@Wtr+btr)
        f32x4 acc[4] = {zero4(), zero4(), zero4(), zero4()};
        gemm_gB<256, 512>(smem + TMPA_OFF, wtr0, wtr1, wtr2, wtr3, l15, kg, acc);
        float ng[16];
        #pragma unroll
        for (int q = 0; q < 16; ++q)
          ng[q] = v[q] - alpha * (acc[q >> 2][q & 3] + btrv[q >> 2]);
        if (n < 8) gh_write(gh, n, ng);
        else { _Pragma("unroll") for (int q = 0; q < 16; ++q) G8[q] = ng[q]; }
      }
      __syncthreads();                       // tr-readers of tmpA done
    }
  }

  // ---- head: feats = [g8 | l1]; h = relu(feats @ W1 + b1) ----
  store16(smem + TMPA_OFF, w, l15, kg, G8);
  __syncthreads();
  {
    f32x4 acc[4] = {zero4(), zero4(), zero4(), zero4()};
    const f16* p0 = W1T + (size_t)(w * 64 +  0 + l15) * 512 + kg * 8;
    const f16* p1 = W1T + (size_t)(w * 64 + 16 + l15) * 512 + kg * 8;
    const f16* p2 = W1T + (size_t)(w * 64 + 32 + l15) * 512 + kg * 8;
    const f16* p3 = W1T + (size_t)(w * 64 + 48 + l15) * 512 + kg * 8;
    #pragma unroll
    for (int ks = 0; ks < 16; ++ks) {
      const int kk = (ks << 5) + (kg << 3);
      const char* base = (ks < 8) ? (smem + TMPA_OFF) : LIQP(1);  // g8 | l[1]
      const int kl = kk & 255;
      f16x8 a = *(const f16x8*)(base + l15 * 512 + ((kl * 2) ^ sw));
      acc[0] = mfma16(a, *(const f16x8*)(p0 + (ks << 5)), acc[0]);
      acc[1] = mfma16(a, *(const f16x8*)(p1 + (ks << 5)), acc[1]);
      acc[2] = mfma16(a, *(const f16x8*)(p2 + (ks << 5)), acc[2]);
      acc[3] = mfma16(a, *(const f16x8*)(p3 + (ks << 5)), acc[3]);
    }
    float H[16];
    #pragma unroll
    for (int q = 0; q < 16; ++q) {
      const float bv = b1p[w * 64 + ((q >> 2) << 4) + l15];
      float v2 = acc[q >> 2][q & 3] + bv;
      H[q] = v2 > 0.f ? v2 : 0.f;
    }
    store16(smem + TMPH_OFF, w, l15, kg, H);
  }
  __syncthreads();

  // ---- out = h @ W2 + b2 (63 col-frags over 4 waves) ----
  f32x4 cf[16];
  #pragma unroll
  for (int fi = 0; fi < 16; ++fi) {
    cf[fi] = zero4();
    const int f = w + fi * 4;
    if (f < 63) {
      const f16* p = W2T + (size_t)(f * 16 + l15) * 256 + kg * 8;
      #pragma unroll
      for (int ks = 0; ks < 8; ++ks) {
        const int kk = (ks << 5) + (kg << 3);
        f16x8 a = *(const f16x8*)(smem + TMPH_OFF + l15 * 512 + ((kk * 2) ^ sw));
        cf[fi] = mfma16(a, *(const f16x8*)(p + (ks << 5)), cf[fi]);
      }
    }
  }
  __syncthreads();                           // GEMM1/L1 reads long done

  // ---- stage out tile [16][1000] f32 in liquid area, coalesced copy ----
  {
    float* ob = (float*)smem;
    #pragma unroll
    for (int fi = 0; fi < 16; ++fi) {
      const int f = w + fi * 4;
      const int colc = f * 16 + l15;
      if (f < 63 && colc < 1000) {
        const float bv = b2p[colc];
        #pragma unroll
        for (int j = 0; j < 4; ++j)
          ob[(kg * 4 + j) * 1000 + colc] = cf[fi][j] + bv;
      }
    }
  }
  __syncthreads();
  {
    const float* ob = (const float*)smem;
    float* op = out + (size_t)r0 * 1000;
    #pragma unroll 1
    for (int i = tid; i < 4000; i += NT)
      *(float4*)(op + i * 4) = *(const float4*)(ob + i * 4);
  }
}

extern "C" void kernel_launch(void* const* d_in, const int* in_sizes, int n_in,
                              void* d_out, int out_size, void* d_ws, size_t ws_size,
                              hipStream_t stream) {
  const float* x   = (const float*)d_in[0];
  const float* Wge = (const float*)d_in[1];
  const float* bge = (const float*)d_in[2];
  const float* Weq = (const float*)d_in[3];
  const float* beq = (const float*)d_in[4];
  const float* Wtr = (const float*)d_in[5];
  const float* btr = (const float*)d_in[6];
  const float* Wab = (const float*)d_in[7];
  const float* bab = (const float*)d_in[8];
  const float* alp = (const float*)d_in[9];
  const float* W1  = (const float*)d_in[10];
  const float* b1  = (const float*)d_in[11];
  const float* W2  = (const float*)d_in[12];
  const float* b2  = (const float*)d_in[13];
  float* out = (float*)d_out;

  char* ws = (char*)d_ws;
  f16* WgeT  = (f16*)(ws + 0);         // 256 x 512
  f16* WeqT  = (f16*)(ws + 262144);    // 256 x 256
  f16* WtrT  = (f16*)(ws + 393216);    // 256 x 256
  f16* W1T   = (f16*)(ws + 524288);    // 256 x 512
  f16* W2T   = (f16*)(ws + 786432);    // 1024 x 256 (rows >= 1000 zero)
  f16* WtabT = (f16*)(ws + 1310720);   // 256 x 256
  float* btabp = (float*)(ws + 1441792);

  prep_all<<<640, 256, 0, stream>>>(Wge, Weq, Wtr, W1, W2,
                                    WgeT, WeqT, WtrT, W1T, W2T);
  prep_wtab<<<256, 256, 0, stream>>>(Wtr, Wab, btr, bab, alp, WtabT, btabp);

  (void)hipFuncSetAttribute(reinterpret_cast<const void*>(cfn_main),
                            hipFuncAttributeMaxDynamicSharedMemorySize, LDS_BYTES);
  cfn_main<<<16384 / TILE_B, NT, LDS_BYTES, stream>>>(
      x, bge, beq, btr, alp, b1, b2,
      WgeT, WeqT, WtrT, WtabT, btabp, W1T, W2T, out);
}